// Round 1
// baseline (875.790 us; speedup 1.0000x reference)
//
#include <hip/hip_runtime.h>

#define XS 128
#define X3 (128 * 128 * 128)

// ---------------------------------------------------------------------------
// Scatter: one thread per index n; loops over batch chunk adding values into
// the dense grid. For fixed b, lanes read consecutive values[b*N+n] (coalesced).
// ---------------------------------------------------------------------------
__global__ __launch_bounds__(256) void scatter_kernel(
    const int* __restrict__ idx,
    const float* __restrict__ vals,   // already offset to batch-chunk start
    float* __restrict__ grid,
    int N, int BC)
{
    int n = blockIdx.x * blockDim.x + threadIdx.x;
    if (n >= N) return;
    int z = idx[3 * n + 0];
    int y = idx[3 * n + 1];
    int x = idx[3 * n + 2];
    int flat = (z * XS + y) * XS + x;
    for (int b = 0; b < BC; ++b) {
        atomicAdd(grid + (size_t)b * X3 + flat, vals[(size_t)b * N + n]);
    }
}

// ---------------------------------------------------------------------------
// Reduce: one block per (local batch, z) plane; one thread per y row.
// Each thread streams its row as float4, computing:
//   d3 (x-diffs) fully in-register,
//   d2 (y-diffs) vs row y+1 (same plane, cache-hot),
//   d1 (z-diffs) vs plane z+1 row y.
// Block-reduces tv and mse, then one scaled atomicAdd per block into d_out.
// ---------------------------------------------------------------------------
__global__ __launch_bounds__(128) void reduce_kernel(
    const float* __restrict__ grid,
    float* __restrict__ out,
    int B, int b0)
{
    const int bl = blockIdx.x >> 7;   // local batch index within chunk
    const int z  = blockIdx.x & 127;
    const int y  = threadIdx.x;       // 0..127

    const float* base = grid + ((size_t)bl * XS + z) * (XS * XS) + (size_t)y * XS;
    const float4* r0 = (const float4*)(base);
    const float4* r1 = (const float4*)(base + XS);        // y+1 row
    const float4* rz = (const float4*)(base + XS * XS);   // z+1 plane, same y

    const bool hasY = (y < XS - 1);
    const bool hasZ = (z < XS - 1);

    float tv = 0.f, mse = 0.f;
    float prev = 0.f;

    #pragma unroll 4
    for (int c = 0; c < XS / 4; ++c) {
        float4 a = r0[c];
        float d;
        if (c != 0) { d = a.x - prev; tv += fabsf(d); mse += d * d; }
        d = a.y - a.x; tv += fabsf(d); mse += d * d;
        d = a.z - a.y; tv += fabsf(d); mse += d * d;
        d = a.w - a.z; tv += fabsf(d); mse += d * d;
        prev = a.w;
        if (hasY) {
            float4 u = r1[c];
            d = u.x - a.x; tv += fabsf(d); mse += d * d;
            d = u.y - a.y; tv += fabsf(d); mse += d * d;
            d = u.z - a.z; tv += fabsf(d); mse += d * d;
            d = u.w - a.w; tv += fabsf(d); mse += d * d;
        }
        if (hasZ) {
            float4 u = rz[c];
            d = u.x - a.x; tv += fabsf(d); mse += d * d;
            d = u.y - a.y; tv += fabsf(d); mse += d * d;
            d = u.z - a.z; tv += fabsf(d); mse += d * d;
            d = u.w - a.w; tv += fabsf(d); mse += d * d;
        }
    }

    // wave reduce (64-wide)
    #pragma unroll
    for (int o = 32; o > 0; o >>= 1) {
        tv  += __shfl_down(tv, o);
        mse += __shfl_down(mse, o);
    }
    __shared__ float stv[2], sms[2];
    const int wid = threadIdx.x >> 6;
    if ((threadIdx.x & 63) == 0) { stv[wid] = tv; sms[wid] = mse; }
    __syncthreads();
    if (threadIdx.x == 0) {
        float t = stv[0] + stv[1];
        float m = sms[0] + sms[1];
        // normalizers: tv / X^3 ; mse / (2*X*X - 2*X)
        atomicAdd(out + (b0 + bl),     t * (1.0f / (float)X3));
        atomicAdd(out + B + (b0 + bl), m * (1.0f / (float)(2 * XS * XS - 2 * XS)));
    }
}

extern "C" void kernel_launch(void* const* d_in, const int* in_sizes, int n_in,
                              void* d_out, int out_size, void* d_ws, size_t ws_size,
                              hipStream_t stream)
{
    const int*   indices = (const int*)d_in[0];
    const float* values  = (const float*)d_in[1];
    const int N = in_sizes[0] / 3;          // 500000
    const int B = in_sizes[1] / N;          // 16
    float* out  = (float*)d_out;
    float* grid = (float*)d_ws;

    const size_t bytes_per_b = (size_t)X3 * sizeof(float);

    // Batch chunk size that fits the workspace (normally BC == B).
    int BC = B;
    while (BC > 1 && (size_t)BC * bytes_per_b > ws_size) BC >>= 1;

    hipMemsetAsync(d_out, 0, (size_t)out_size * sizeof(float), stream);

    for (int b0 = 0; b0 < B; b0 += BC) {
        const int bc = (B - b0 < BC) ? (B - b0) : BC;
        hipMemsetAsync(grid, 0, (size_t)bc * bytes_per_b, stream);
        scatter_kernel<<<(N + 255) / 256, 256, 0, stream>>>(
            indices, values + (size_t)b0 * N, grid, N, bc);
        reduce_kernel<<<bc * XS, XS, 0, stream>>>(grid, out, B, b0);
    }
}

// Round 2
// 628.533 us; speedup vs baseline: 1.3934x; 1.3934x over previous
//
#include <hip/hip_runtime.h>

#define XS 128
#define X3 (XS * XS * XS)

// ---------------------------------------------------------------------------
// Scatter into grid laid out [X3][BC] (batch innermost): the BC atomics from
// one index land in one 64B cache line instead of BC random lines.
// ---------------------------------------------------------------------------
__global__ __launch_bounds__(256) void scatter_kernel(
    const int* __restrict__ idx,
    const float* __restrict__ vals,   // already offset to batch-chunk start
    float* __restrict__ grid,         // [X3][BC]
    int N, int BC)
{
    int n = blockIdx.x * blockDim.x + threadIdx.x;
    if (n >= N) return;
    int z = idx[3 * n + 0];
    int y = idx[3 * n + 1];
    int x = idx[3 * n + 2];
    int flat = (z * XS + y) * XS + x;
    float* g = grid + (size_t)flat * BC;
    #pragma unroll 8
    for (int b = 0; b < BC; ++b) {
        atomicAdd(g + b, vals[(size_t)b * N + n]);
    }
}

// ---------------------------------------------------------------------------
// Reduce over grid [X3][BV float4s]: lane t handles (voxel = t>>logBV,
// batch-group j = t&(BV-1)). All loads coalesced. Forward diffs along
// x (v+1), y (v+XS), z (v+XS*XS), accumulated per-lane as float4 (4 batches).
// ---------------------------------------------------------------------------
__global__ __launch_bounds__(256) void reduce_kernel(
    const float4* __restrict__ G,     // [X3][BV]
    float* __restrict__ out,          // [2][Btot]
    int Btot, int b0, int BV, int logBV)
{
    const int t = blockIdx.x * blockDim.x + threadIdx.x;
    const int j = t & (BV - 1);
    const int vstride = (gridDim.x * blockDim.x) >> logBV;

    float4 tv = {0.f, 0.f, 0.f, 0.f};
    float4 ms = {0.f, 0.f, 0.f, 0.f};

    for (int v = t >> logBV; v < X3; v += vstride) {
        const int x = v & (XS - 1);
        const int y = (v >> 7) & (XS - 1);
        const int z = v >> 14;
        const float4 s = G[(size_t)v * BV + j];

        if (x < XS - 1) {
            float4 nb = G[(size_t)(v + 1) * BV + j];
            float d;
            d = nb.x - s.x; tv.x += fabsf(d); ms.x += d * d;
            d = nb.y - s.y; tv.y += fabsf(d); ms.y += d * d;
            d = nb.z - s.z; tv.z += fabsf(d); ms.z += d * d;
            d = nb.w - s.w; tv.w += fabsf(d); ms.w += d * d;
        }
        if (y < XS - 1) {
            float4 nb = G[(size_t)(v + XS) * BV + j];
            float d;
            d = nb.x - s.x; tv.x += fabsf(d); ms.x += d * d;
            d = nb.y - s.y; tv.y += fabsf(d); ms.y += d * d;
            d = nb.z - s.z; tv.z += fabsf(d); ms.z += d * d;
            d = nb.w - s.w; tv.w += fabsf(d); ms.w += d * d;
        }
        if (z < XS - 1) {
            float4 nb = G[(size_t)(v + XS * XS) * BV + j];
            float d;
            d = nb.x - s.x; tv.x += fabsf(d); ms.x += d * d;
            d = nb.y - s.y; tv.y += fabsf(d); ms.y += d * d;
            d = nb.z - s.z; tv.z += fabsf(d); ms.z += d * d;
            d = nb.w - s.w; tv.w += fabsf(d); ms.w += d * d;
        }
    }

    // Cross-lane reduce: fold lanes with identical j (strides are multiples
    // of BV, so the j-class is preserved).
    for (int o = 32; o >= BV; o >>= 1) {
        tv.x += __shfl_down(tv.x, o); tv.y += __shfl_down(tv.y, o);
        tv.z += __shfl_down(tv.z, o); tv.w += __shfl_down(tv.w, o);
        ms.x += __shfl_down(ms.x, o); ms.y += __shfl_down(ms.y, o);
        ms.z += __shfl_down(ms.z, o); ms.w += __shfl_down(ms.w, o);
    }

    __shared__ float4 stv[4][16];
    __shared__ float4 sms[4][16];
    const int wid  = threadIdx.x >> 6;
    const int lane = threadIdx.x & 63;
    if (lane < BV) { stv[wid][lane] = tv; sms[wid][lane] = ms; }
    __syncthreads();

    const int nw = blockDim.x >> 6;
    if ((int)threadIdx.x < BV) {
        float4 t4 = stv[0][threadIdx.x];
        float4 m4 = sms[0][threadIdx.x];
        for (int w = 1; w < nw; ++w) {
            float4 a = stv[w][threadIdx.x], b = sms[w][threadIdx.x];
            t4.x += a.x; t4.y += a.y; t4.z += a.z; t4.w += a.w;
            m4.x += b.x; m4.y += b.y; m4.z += b.z; m4.w += b.w;
        }
        const float ktv = 1.0f / (float)X3;
        const float kms = 1.0f / (float)(2 * XS * XS - 2 * XS);
        const int b = b0 + (int)threadIdx.x * 4;
        atomicAdd(out + b + 0, t4.x * ktv);
        atomicAdd(out + b + 1, t4.y * ktv);
        atomicAdd(out + b + 2, t4.z * ktv);
        atomicAdd(out + b + 3, t4.w * ktv);
        atomicAdd(out + Btot + b + 0, m4.x * kms);
        atomicAdd(out + Btot + b + 1, m4.y * kms);
        atomicAdd(out + Btot + b + 2, m4.z * kms);
        atomicAdd(out + Btot + b + 3, m4.w * kms);
    }
}

// ---------------------------------------------------------------------------
// Correctness-only fallback for BC not a usable power-of-two multiple of 4:
// gridDim.y = batch, grid-stride over voxels, scalar accumulation.
// ---------------------------------------------------------------------------
__global__ __launch_bounds__(256) void reduce_fallback(
    const float* __restrict__ G,      // [X3][BC]
    float* __restrict__ out,
    int Btot, int b0, int BC)
{
    const int b = blockIdx.y;
    float tv = 0.f, ms = 0.f;
    for (int v = blockIdx.x * blockDim.x + threadIdx.x; v < X3;
         v += gridDim.x * blockDim.x) {
        const int x = v & (XS - 1);
        const int y = (v >> 7) & (XS - 1);
        const int z = v >> 14;
        const float s = G[(size_t)v * BC + b];
        float d;
        if (x < XS - 1) { d = G[(size_t)(v + 1) * BC + b] - s;        tv += fabsf(d); ms += d * d; }
        if (y < XS - 1) { d = G[(size_t)(v + XS) * BC + b] - s;       tv += fabsf(d); ms += d * d; }
        if (z < XS - 1) { d = G[(size_t)(v + XS * XS) * BC + b] - s;  tv += fabsf(d); ms += d * d; }
    }
    for (int o = 32; o > 0; o >>= 1) { tv += __shfl_down(tv, o); ms += __shfl_down(ms, o); }
    __shared__ float stv[4], sms[4];
    if ((threadIdx.x & 63) == 0) { stv[threadIdx.x >> 6] = tv; sms[threadIdx.x >> 6] = ms; }
    __syncthreads();
    if (threadIdx.x == 0) {
        float t = 0.f, m = 0.f;
        for (int w = 0; w < (int)(blockDim.x >> 6); ++w) { t += stv[w]; m += sms[w]; }
        atomicAdd(out + b0 + b, t / (float)X3);
        atomicAdd(out + Btot + b0 + b, m / (float)(2 * XS * XS - 2 * XS));
    }
}

extern "C" void kernel_launch(void* const* d_in, const int* in_sizes, int n_in,
                              void* d_out, int out_size, void* d_ws, size_t ws_size,
                              hipStream_t stream)
{
    const int*   indices = (const int*)d_in[0];
    const float* values  = (const float*)d_in[1];
    const int N = in_sizes[0] / 3;          // 500000
    const int B = in_sizes[1] / N;          // 16
    float* out  = (float*)d_out;
    float* grid = (float*)d_ws;

    const size_t bytes_per_b = (size_t)X3 * sizeof(float);

    int BC = B;
    while (BC > 1 && (size_t)BC * bytes_per_b > ws_size) BC >>= 1;

    hipMemsetAsync(d_out, 0, (size_t)out_size * sizeof(float), stream);

    for (int b0 = 0; b0 < B; b0 += BC) {
        const int bc = (B - b0 < BC) ? (B - b0) : BC;
        hipMemsetAsync(grid, 0, (size_t)bc * bytes_per_b, stream);
        scatter_kernel<<<(N + 255) / 256, 256, 0, stream>>>(
            indices, values + (size_t)b0 * N, grid, N, bc);

        const int BV = bc / 4;
        const bool pow2 = (BV > 0) && ((BV & (BV - 1)) == 0) && (bc % 4 == 0) && (BV <= 16);
        if (pow2) {
            int logBV = 0; while ((1 << logBV) < BV) ++logBV;
            reduce_kernel<<<2048, 256, 0, stream>>>(
                (const float4*)grid, out, B, b0, BV, logBV);
        } else {
            dim3 g(1024, bc);
            reduce_fallback<<<g, 256, 0, stream>>>(grid, out, B, b0, bc);
        }
    }
}

// Round 4
// 267.265 us; speedup vs baseline: 3.2769x; 2.3517x over previous
//
#include <hip/hip_runtime.h>

#define XS 128
#define PLANE (XS * XS)            // 16384
#define X3 (XS * XS * XS)          // 2097152
#define ROWP 129                   // padded LDS row stride (floats)
#define RCHUNK 2048                // indices per reorder block

// ---------------------------------------------------------------------------
// Pass 1: histogram of z over all indices (128 bins).
// ---------------------------------------------------------------------------
__global__ __launch_bounds__(256) void hist_kernel(
    const int* __restrict__ idx, int* __restrict__ hist, int N)
{
    __shared__ int lh[XS];
    for (int i = threadIdx.x; i < XS; i += blockDim.x) lh[i] = 0;
    __syncthreads();
    for (int n = blockIdx.x * blockDim.x + threadIdx.x; n < N;
         n += gridDim.x * blockDim.x)
        atomicAdd(&lh[idx[3 * n]], 1);
    __syncthreads();
    for (int i = threadIdx.x; i < XS; i += blockDim.x)
        if (lh[i]) atomicAdd(&hist[i], lh[i]);
}

// ---------------------------------------------------------------------------
// Pass 2: exclusive scan of the 128 bins (trivial single-thread).
// ---------------------------------------------------------------------------
__global__ void scan_kernel(const int* __restrict__ hist,
                            int* __restrict__ base, int* __restrict__ cursor)
{
    if (threadIdx.x == 0) {
        int acc = 0;
        for (int i = 0; i < XS; ++i) {
            base[i] = acc; cursor[i] = acc; acc += hist[i];
        }
    }
}

// ---------------------------------------------------------------------------
// Pass 3: reorder indices into per-z lists. Block-local histogram reserves a
// contiguous range per bin (few global atomics). Entry: int2 {n, (y<<7)|x}.
// ---------------------------------------------------------------------------
__global__ __launch_bounds__(256) void reorder_kernel(
    const int* __restrict__ idx, int* __restrict__ cursor,
    int2* __restrict__ list, int N)
{
    __shared__ int lh[XS], lbase[XS];
    const int c0 = blockIdx.x * RCHUNK;
    const int c1 = (c0 + RCHUNK < N) ? c0 + RCHUNK : N;

    for (int i = threadIdx.x; i < XS; i += blockDim.x) lh[i] = 0;
    __syncthreads();
    for (int n = c0 + threadIdx.x; n < c1; n += blockDim.x)
        atomicAdd(&lh[idx[3 * n]], 1);
    __syncthreads();
    for (int i = threadIdx.x; i < XS; i += blockDim.x) {
        lbase[i] = lh[i] ? atomicAdd(&cursor[i], lh[i]) : 0;
        lh[i] = 0;
    }
    __syncthreads();
    for (int n = c0 + threadIdx.x; n < c1; n += blockDim.x) {
        const int z = idx[3 * n], y = idx[3 * n + 1], x = idx[3 * n + 2];
        const int r = atomicAdd(&lh[z], 1);
        list[lbase[z] + r] = make_int2(n, (y << 7) | x);
    }
}

// ---------------------------------------------------------------------------
// Pass 4: slab kernel. Block = (local batch b, z). Builds the 128x128 slab in
// LDS via LDS atomics, computes x-diff and y-diff TV/MSE from LDS, streams the
// slab to grid[b][z] coalesced. No global atomics on the grid, no grid memset.
// ---------------------------------------------------------------------------
__global__ __launch_bounds__(256) void slab_kernel(
    const int2* __restrict__ list, const int* __restrict__ base,
    const int* __restrict__ cnt, const float* __restrict__ vals,
    float* __restrict__ grid,      // [BC][X3]
    float* __restrict__ out,       // [2][Btot]
    int N, int Btot, int b0)
{
    __shared__ float slab[XS * ROWP];
    __shared__ float rtv[4], rms[4];
    const int b = blockIdx.x;      // local batch
    const int z = blockIdx.y;

    for (int i = threadIdx.x; i < XS * ROWP; i += 256) slab[i] = 0.f;
    __syncthreads();

    const int c  = cnt[z];
    const int s0 = base[z];
    const float* vb = vals + (size_t)(b0 + b) * N;
    for (int e = threadIdx.x; e < c; e += 256) {
        const int2 en = list[s0 + e];
        atomicAdd(&slab[(en.y >> 7) * ROWP + (en.y & 127)], vb[en.x]);
    }
    __syncthreads();

    float tv = 0.f, ms = 0.f;
    for (int cc = threadIdx.x; cc < PLANE; cc += 256) {
        const int y = cc >> 7, x = cc & 127;
        const float s = slab[y * ROWP + x];
        if (x < XS - 1) {
            const float d = slab[y * ROWP + x + 1] - s;
            tv += fabsf(d); ms += d * d;
        }
        if (y < XS - 1) {
            const float d = slab[(y + 1) * ROWP + x] - s;
            tv += fabsf(d); ms += d * d;
        }
    }

    // stream slab to global, coalesced float4
    float4* gb = (float4*)(grid + (size_t)b * X3 + (size_t)z * PLANE);
    for (int q = threadIdx.x; q < PLANE / 4; q += 256) {
        const int y = q >> 5, x4 = (q & 31) * 4;
        const float* r = &slab[y * ROWP + x4];
        gb[q] = make_float4(r[0], r[1], r[2], r[3]);
    }

    for (int o = 32; o > 0; o >>= 1) {
        tv += __shfl_down(tv, o); ms += __shfl_down(ms, o);
    }
    if ((threadIdx.x & 63) == 0) {
        rtv[threadIdx.x >> 6] = tv; rms[threadIdx.x >> 6] = ms;
    }
    __syncthreads();
    if (threadIdx.x == 0) {
        const float t = rtv[0] + rtv[1] + rtv[2] + rtv[3];
        const float m = rms[0] + rms[1] + rms[2] + rms[3];
        atomicAdd(out + (b0 + b),        t * (1.0f / (float)X3));
        atomicAdd(out + Btot + (b0 + b), m * (1.0f / (float)(2 * XS * XS - 2 * XS)));
    }
}

// ---------------------------------------------------------------------------
// Pass 5: z-diffs only. Coalesced float4 streaming of plane v and v+1.
// ---------------------------------------------------------------------------
__global__ __launch_bounds__(256) void zdiff_kernel(
    const float4* __restrict__ grid,  // [BC][X3/4]
    float* __restrict__ out, int Btot, int b0)
{
    __shared__ float rtv[4], rms[4];
    const int b = blockIdx.y;
    const float4* G = grid + (size_t)b * (X3 / 4);

    float tv = 0.f, ms = 0.f;
    for (int v = blockIdx.x * blockDim.x + threadIdx.x; v < X3 / 4;
         v += gridDim.x * blockDim.x) {
        const int z = v >> 12;                 // PLANE/4 = 4096
        if (z == XS - 1) continue;
        const float4 a = G[v];
        const float4 c = G[v + PLANE / 4];
        float d;
        d = c.x - a.x; tv += fabsf(d); ms += d * d;
        d = c.y - a.y; tv += fabsf(d); ms += d * d;
        d = c.z - a.z; tv += fabsf(d); ms += d * d;
        d = c.w - a.w; tv += fabsf(d); ms += d * d;
    }

    for (int o = 32; o > 0; o >>= 1) {
        tv += __shfl_down(tv, o); ms += __shfl_down(ms, o);
    }
    if ((threadIdx.x & 63) == 0) {
        rtv[threadIdx.x >> 6] = tv; rms[threadIdx.x >> 6] = ms;
    }
    __syncthreads();
    if (threadIdx.x == 0) {
        const float t = rtv[0] + rtv[1] + rtv[2] + rtv[3];
        const float m = rms[0] + rms[1] + rms[2] + rms[3];
        atomicAdd(out + (b0 + b),        t * (1.0f / (float)X3));
        atomicAdd(out + Btot + (b0 + b), m * (1.0f / (float)(2 * XS * XS - 2 * XS)));
    }
}

extern "C" void kernel_launch(void* const* d_in, const int* in_sizes, int n_in,
                              void* d_out, int out_size, void* d_ws, size_t ws_size,
                              hipStream_t stream)
{
    const int*   indices = (const int*)d_in[0];
    const float* values  = (const float*)d_in[1];
    const int N = in_sizes[0] / 3;          // 500000
    const int B = in_sizes[1] / N;          // 16
    float* out = (float*)d_out;
    char*  ws  = (char*)d_ws;

    // ws layout: [list int2 * N][hist 128][base 128][cursor 128][grid BC*X3]
    size_t off = (size_t)N * sizeof(int2);
    int2* list   = (int2*)ws;
    int*  hist   = (int*)(ws + off);
    int*  basep  = hist + XS;
    int*  cursor = basep + XS;
    size_t goff  = (off + 3 * XS * sizeof(int) + 255) & ~(size_t)255;
    float* grid  = (float*)(ws + goff);

    const size_t bytes_per_b = (size_t)X3 * sizeof(float);
    size_t avail = (ws_size > goff) ? ws_size - goff : 0;
    int BC = (int)(avail / bytes_per_b);
    if (BC > B) BC = B;
    if (BC < 1) BC = 1;   // harness workspace is known to hold >= one grid

    hipMemsetAsync(d_out, 0, (size_t)out_size * sizeof(float), stream);
    hipMemsetAsync(hist, 0, XS * sizeof(int), stream);

    hist_kernel<<<256, 256, 0, stream>>>(indices, hist, N);
    scan_kernel<<<1, 64, 0, stream>>>(hist, basep, cursor);
    reorder_kernel<<<(N + RCHUNK - 1) / RCHUNK, 256, 0, stream>>>(
        indices, cursor, list, N);

    for (int b0 = 0; b0 < B; b0 += BC) {
        const int bc = (B - b0 < BC) ? (B - b0) : BC;
        slab_kernel<<<dim3(bc, XS), 256, 0, stream>>>(
            list, basep, hist, values, grid, out, N, B, b0);
        zdiff_kernel<<<dim3(256, bc), 256, 0, stream>>>(
            (const float4*)grid, out, B, b0);
    }
}

// Round 5
// 176.349 us; speedup vs baseline: 4.9662x; 1.5155x over previous
//
#include <hip/hip_runtime.h>

#define XS 128
#define PLANE (XS * XS)            // 16384
#define X3 (XS * XS * XS)          // 2097152
#define ZC 8                       // planes per chunk (block)
#define RCHUNK 2048                // indices per reorder block

// ---------------------------------------------------------------------------
// Pass 1: histogram of z over all indices (128 bins).
// ---------------------------------------------------------------------------
__global__ __launch_bounds__(256) void hist_kernel(
    const int* __restrict__ idx, int* __restrict__ hist, int N)
{
    __shared__ int lh[XS];
    for (int i = threadIdx.x; i < XS; i += blockDim.x) lh[i] = 0;
    __syncthreads();
    for (int n = blockIdx.x * blockDim.x + threadIdx.x; n < N;
         n += gridDim.x * blockDim.x)
        atomicAdd(&lh[idx[3 * n]], 1);
    __syncthreads();
    for (int i = threadIdx.x; i < XS; i += blockDim.x)
        if (lh[i]) atomicAdd(&hist[i], lh[i]);
}

// ---------------------------------------------------------------------------
// Pass 2: exclusive scan of the 128 bins (trivial single-thread).
// ---------------------------------------------------------------------------
__global__ void scan_kernel(const int* __restrict__ hist,
                            int* __restrict__ base, int* __restrict__ cursor)
{
    if (threadIdx.x == 0) {
        int acc = 0;
        for (int i = 0; i < XS; ++i) {
            base[i] = acc; cursor[i] = acc; acc += hist[i];
        }
    }
}

// ---------------------------------------------------------------------------
// Pass 3: reorder indices into per-z lists. Block-local histogram reserves a
// contiguous range per bin (few global atomics). Entry: int2 {n, (y<<7)|x}.
// ---------------------------------------------------------------------------
__global__ __launch_bounds__(256) void reorder_kernel(
    const int* __restrict__ idx, int* __restrict__ cursor,
    int2* __restrict__ list, int N)
{
    __shared__ int lh[XS], lbase[XS];
    const int c0 = blockIdx.x * RCHUNK;
    const int c1 = (c0 + RCHUNK < N) ? c0 + RCHUNK : N;

    for (int i = threadIdx.x; i < XS; i += blockDim.x) lh[i] = 0;
    __syncthreads();
    for (int n = c0 + threadIdx.x; n < c1; n += blockDim.x)
        atomicAdd(&lh[idx[3 * n]], 1);
    __syncthreads();
    for (int i = threadIdx.x; i < XS; i += blockDim.x) {
        lbase[i] = lh[i] ? atomicAdd(&cursor[i], lh[i]) : 0;
        lh[i] = 0;
    }
    __syncthreads();
    for (int n = c0 + threadIdx.x; n < c1; n += blockDim.x) {
        const int z = idx[3 * n], y = idx[3 * n + 1], x = idx[3 * n + 2];
        const int r = atomicAdd(&lh[z], 1);
        list[lbase[z] + r] = make_int2(n, (y << 7) | x);
    }
}

// ---------------------------------------------------------------------------
// Pass 4 (fused): block = (batch b, z-chunk). Two LDS plane buffers ping-pong:
// build plane z+1 via LDS atomics while computing x/y diffs of plane z and the
// z-diff (z, z+1) straight from LDS. The dense grid never exists in global
// memory. Chunk also builds its boundary plane (z0+ZC) for the last z-diff.
// ---------------------------------------------------------------------------
__global__ __launch_bounds__(1024, 4) void fused_kernel(
    const int2* __restrict__ list, const int* __restrict__ base,
    const int* __restrict__ cnt, const float* __restrict__ vals,
    float* __restrict__ out,       // [2][B]
    int N, int Btot)
{
    __shared__ float buf[2][PLANE];          // 128 KB (< 160 KB/CU) -> 1 blk/CU
    __shared__ float rtv[16], rms[16];

    const int b    = blockIdx.x;
    const int z0   = blockIdx.y * ZC;
    const int tid  = threadIdx.x;
    const float* vb = vals + (size_t)b * N;

    float tv = 0.f, ms = 0.f;

    // --- build plane z0 into buf[0] ---
    for (int i = tid; i < PLANE; i += 1024) buf[0][i] = 0.f;
    __syncthreads();
    {
        const int s0 = base[z0], c = cnt[z0];
        int e = tid;
        for (; e + 3072 < c; e += 4096) {
            int2 e0 = list[s0 + e], e1 = list[s0 + e + 1024];
            int2 e2 = list[s0 + e + 2048], e3 = list[s0 + e + 3072];
            float v0 = vb[e0.x], v1 = vb[e1.x], v2 = vb[e2.x], v3 = vb[e3.x];
            atomicAdd(&buf[0][e0.y], v0); atomicAdd(&buf[0][e1.y], v1);
            atomicAdd(&buf[0][e2.y], v2); atomicAdd(&buf[0][e3.y], v3);
        }
        for (; e < c; e += 1024) {
            int2 en = list[s0 + e];
            atomicAdd(&buf[0][en.y], vb[en.x]);
        }
    }
    __syncthreads();

    // --- pipeline over planes z0..z0+ZC-1 ---
    for (int k = 1; k <= ZC; ++k) {
        float* cur = buf[(k - 1) & 1];
        float* nxt = buf[k & 1];
        const int z = z0 + k;                // plane to build
        const bool haveNext = (z < XS);

        if (haveNext) {
            for (int i = tid; i < PLANE; i += 1024) nxt[i] = 0.f;
        }
        __syncthreads();
        if (haveNext) {
            const int s0 = base[z], c = cnt[z];
            int e = tid;
            for (; e + 3072 < c; e += 4096) {
                int2 e0 = list[s0 + e], e1 = list[s0 + e + 1024];
                int2 e2 = list[s0 + e + 2048], e3 = list[s0 + e + 3072];
                float v0 = vb[e0.x], v1 = vb[e1.x], v2 = vb[e2.x], v3 = vb[e3.x];
                atomicAdd(&nxt[e0.y], v0); atomicAdd(&nxt[e1.y], v1);
                atomicAdd(&nxt[e2.y], v2); atomicAdd(&nxt[e3.y], v3);
            }
            for (; e < c; e += 1024) {
                int2 en = list[s0 + e];
                atomicAdd(&nxt[en.y], vb[en.x]);
            }
        }
        __syncthreads();

        // --- diffs for plane z0+k-1 (owned): x, y always; z vs nxt ---
        const float4* c4 = (const float4*)cur;
        const float4* n4 = (const float4*)nxt;
        for (int q = tid; q < PLANE / 4; q += 1024) {
            const int qx = q & 31;           // quad-x
            const int y  = q >> 5;
            const float4 a = c4[q];
            float d;
            d = a.y - a.x; tv += fabsf(d); ms += d * d;
            d = a.z - a.y; tv += fabsf(d); ms += d * d;
            d = a.w - a.z; tv += fabsf(d); ms += d * d;
            if (qx < 31) {
                d = cur[4 * q + 4] - a.w; tv += fabsf(d); ms += d * d;
            }
            if (y < XS - 1) {
                const float4 u = c4[q + 32];
                d = u.x - a.x; tv += fabsf(d); ms += d * d;
                d = u.y - a.y; tv += fabsf(d); ms += d * d;
                d = u.z - a.z; tv += fabsf(d); ms += d * d;
                d = u.w - a.w; tv += fabsf(d); ms += d * d;
            }
            if (haveNext) {
                const float4 u = n4[q];
                d = u.x - a.x; tv += fabsf(d); ms += d * d;
                d = u.y - a.y; tv += fabsf(d); ms += d * d;
                d = u.z - a.z; tv += fabsf(d); ms += d * d;
                d = u.w - a.w; tv += fabsf(d); ms += d * d;
            }
        }
        __syncthreads();   // all reads of cur done before it is re-zeroed
    }

    // --- block reduction (16 waves) ---
    for (int o = 32; o > 0; o >>= 1) {
        tv += __shfl_down(tv, o); ms += __shfl_down(ms, o);
    }
    if ((tid & 63) == 0) { rtv[tid >> 6] = tv; rms[tid >> 6] = ms; }
    __syncthreads();
    if (tid == 0) {
        float t = 0.f, m = 0.f;
        #pragma unroll
        for (int w = 0; w < 16; ++w) { t += rtv[w]; m += rms[w]; }
        atomicAdd(out + b,        t * (1.0f / (float)X3));
        atomicAdd(out + Btot + b, m * (1.0f / (float)(2 * XS * XS - 2 * XS)));
    }
}

extern "C" void kernel_launch(void* const* d_in, const int* in_sizes, int n_in,
                              void* d_out, int out_size, void* d_ws, size_t ws_size,
                              hipStream_t stream)
{
    const int*   indices = (const int*)d_in[0];
    const float* values  = (const float*)d_in[1];
    const int N = in_sizes[0] / 3;          // 500000
    const int B = in_sizes[1] / N;          // 16
    float* out = (float*)d_out;
    char*  ws  = (char*)d_ws;

    // ws layout: [list int2 * N][hist 128][base 128][cursor 128]
    int2* list   = (int2*)ws;
    int*  hist   = (int*)(ws + (size_t)N * sizeof(int2));
    int*  basep  = hist + XS;
    int*  cursor = basep + XS;

    hipMemsetAsync(d_out, 0, (size_t)out_size * sizeof(float), stream);
    hipMemsetAsync(hist, 0, XS * sizeof(int), stream);

    hist_kernel<<<256, 256, 0, stream>>>(indices, hist, N);
    scan_kernel<<<1, 64, 0, stream>>>(hist, basep, cursor);
    reorder_kernel<<<(N + RCHUNK - 1) / RCHUNK, 256, 0, stream>>>(
        indices, cursor, list, N);
    fused_kernel<<<dim3(B, XS / ZC), 1024, 0, stream>>>(
        list, basep, hist, values, out, N, B);
}